// Round 16
// baseline (553.322 us; speedup 1.0000x reference)
//
#include <hip/hip_runtime.h>

// Window attention: B=4096, L=49, C=256, H=8, D=32
// prep : weight swizzle (bf16 MFMA frag order) + bias table [h][q][k]
// kall : fully fused qkv GEMM + attention + proj; one block (512 thr, 8 waves)
//        per window, ONE HEAD PER WAVE.
//
// R16 occupancy push (the R15 math, restructured for registers):
//   QKV GEMM tiled over OUTPUT tiles so only 16 accumulator regs are ever
//   live (qa[2]+ka[2] per query-tile mt, repack immediately; then va[2][2]
//   per mt-pair). Peak live ~110 regs including the 48-reg fragment set --
//   unlike R4/R6-R9, which all held >=48 acc + 48 frags simultaneously and
//   spilled under any cap <=170. Now __launch_bounds__(512,4) (128-reg cap)
//   -> 2 blocks/CU, 4 waves/SIMD (was 1 block, 2 waves: 2/3 of block time
//   was latency stalls). Cost: xs read 2x (64 ds_read_b128), wq 160 L2-hot
//   loads (vs 48). Everything else byte-identical to the passing R15.
// Hard rule from R11-R15 bisection: NEVER feed a fresh VMEM load into an
// MFMA C-operand (R14 fail 3.5e-2); bias stays a VALU add.
// Tripwire: WRITE_SIZE >> 218MB means the cap spilled -> revert to R15.

typedef short s8v __attribute__((ext_vector_type(8)));   // 8 bf16 (4 VGPRs)
typedef short s4v __attribute__((ext_vector_type(4)));   // 4 bf16 (8B)
typedef float f4  __attribute__((ext_vector_type(4)));   // MFMA C/D frag

#define MFMA(a,b,c) __builtin_amdgcn_mfma_f32_16x16x32_bf16((a),(b),(c),0,0,0)

__device__ __forceinline__ unsigned short f2bf(float f) {
    unsigned u = __float_as_uint(f);
    u = u + 0x7fffu + ((u >> 16) & 1u);   // round-to-nearest-even
    return (unsigned short)(u >> 16);
}

// pack 2 f32 -> u32 of 2 bf16 (lo,hi), RNE, single VALU op (R10-proven)
__device__ __forceinline__ unsigned pkbf(float lo, float hi) {
    unsigned r;
    asm("v_cvt_pk_bf16_f32 %0, %1, %2" : "=v"(r) : "v"(lo), "v"(hi));
    return r;
}

// ---------------- prep: weight swizzle + bias table ----------------
// wq layout: [nt=48][ks=8][lane=64][j=8]; element = qkv_w[ks*32+(lane>>4)*8+j][nt*16+(lane&15)]
// wp: same with nt=16 over proj_w
// biasT2: [h=8][query=64][key=64] fp32; key>=49 -> -1e30;
//         padded query (>=49) & key<49 -> 0 (finite softmax sum w/o max-sub)
__global__ void prep(const float* __restrict__ qkv_w, const float* __restrict__ proj_w,
                     const float* __restrict__ rel_bias, const int* __restrict__ rel_idx,
                     unsigned short* __restrict__ wq, unsigned short* __restrict__ wp,
                     float* __restrict__ biasT2)
{
    int idx = blockIdx.x * blockDim.x + threadIdx.x;
    int stride = gridDim.x * blockDim.x;
    for (int i = idx; i < 48*8*64*8; i += stride) {
        int j = i & 7, l = (i >> 3) & 63, ks = (i >> 9) & 7, nt = i >> 12;
        int k = ks*32 + (l >> 4)*8 + j;
        int n = nt*16 + (l & 15);
        wq[i] = f2bf(qkv_w[k*768 + n]);
    }
    for (int i = idx; i < 16*8*64*8; i += stride) {
        int j = i & 7, l = (i >> 3) & 63, ks = (i >> 9) & 7, nt = i >> 12;
        int k = ks*32 + (l >> 4)*8 + j;
        int n = nt*16 + (l & 15);
        wp[i] = f2bf(proj_w[k*256 + n]);
    }
    for (int i = idx; i < 8*64*64; i += stride) {
        int k = i & 63, q = (i >> 6) & 63, h = i >> 12;
        float v;
        if (k < 49) v = (q < 49) ? rel_bias[rel_idx[q*49 + k]*8 + h] : 0.f;
        else        v = -1e30f;
        biasT2[i] = v;
    }
}

// ---------------- kall: fused qkv + attention + proj ----------------
__global__ __launch_bounds__(512, 4) void kall(
    const float* __restrict__ x, const float* __restrict__ qkv_b,
    const unsigned short* __restrict__ wq, const float* __restrict__ biasT2,
    const unsigned short* __restrict__ wp, const float* __restrict__ proj_b,
    float* __restrict__ out)
{
    __shared__ __align__(16) unsigned short xs[4][8][64][8];   // x frags, 32768 B (lane^ks swizzled)
    __shared__ __align__(16) unsigned short osd[64][264];      // O bf16 row-major, 33792 B

    const int b    = blockIdx.x;
    const int tid  = threadIdx.x;
    const int w    = tid >> 6;      // wave = head
    const int lane = tid & 63;
    const int ln   = lane & 15;
    const int g    = lane >> 4;

    // ---- stage x -> frag-layout bf16 LDS (cvt_pk pairs; lane^ks bank swizzle) ----
    const float* xb = x + (size_t)b * (49*256);
    for (int i = tid; i < 4096; i += 512) {
        int r = i >> 6, c4 = i & 63;
        float4 v = make_float4(0.f, 0.f, 0.f, 0.f);
        if (r < 49) v = ((const float4*)xb)[r*64 + c4];
        uint2 o;
        o.x = pkbf(v.x, v.y);
        o.y = pkbf(v.z, v.w);
        int mt = r >> 4, lnr = r & 15;
        int c  = c4 * 4;
        int ks = c >> 5, gg = (c >> 3) & 3, j0 = c & 7;
        *(uint2*)&xs[mt][ks][(gg*16 + lnr) ^ ks][j0] = o;
    }
    __syncthreads();

    const float scale = 0.17677669529663687f;  // 1/sqrt(32)
    const int h = w;                           // this wave's head

    // ---- biases (tiny, loaded up front) ----
    float4 bq[2], bk[2]; float bv[2];
    #pragma unroll
    for (int dh = 0; dh < 2; ++dh) {
        bq[dh] = *(const float4*)&qkv_b[       h*32 + dh*16 + g*4];
        bk[dh] = *(const float4*)&qkv_b[256 +  h*32 + dh*16 + g*4];
        bv[dh] = qkv_b[512 + h*32 + dh*16 + ln];
    }

    s8v qf[4], kf[4], vf[2][2];

    // ---- Q,K GEMM per query-tile mt: only qa[2]+ka[2] (16 regs) live ----
    // qa/ka (transposed): qa[dh][r] = Q[m=mt*16+ln][d=dh*16+g*4+r]
    #pragma unroll
    for (int mt = 0; mt < 4; ++mt) {
        f4 qa[2], ka[2];
        qa[0] = (f4){0.f,0.f,0.f,0.f}; qa[1] = (f4){0.f,0.f,0.f,0.f};
        ka[0] = (f4){0.f,0.f,0.f,0.f}; ka[1] = (f4){0.f,0.f,0.f,0.f};
        #pragma unroll
        for (int ks = 0; ks < 8; ++ks) {
            s8v xf = *(const s8v*)&xs[mt][ks][lane ^ ks][0];
            s8v wfq[2], wfk[2];
            #pragma unroll
            for (int dh = 0; dh < 2; ++dh) {
                wfq[dh] = *(const s8v*)&wq[(size_t)((( 2*h+dh)*8 + ks)*64 + lane) * 8];
                wfk[dh] = *(const s8v*)&wq[(size_t)(((16+2*h+dh)*8 + ks)*64 + lane) * 8];
            }
            #pragma unroll
            for (int dh = 0; dh < 2; ++dh) {
                qa[dh] = MFMA(wfq[dh], xf, qa[dh]);   // transposed
                ka[dh] = MFMA(wfk[dh], xf, ka[dh]);
            }
        }
        // in-lane repack (kappa mapping) via cvt_pk pairs; qa/ka die here
        union { s8v s; unsigned u[4]; } qu, ku;
        qu.u[0] = pkbf((qa[0][0] + bq[0].x)*scale, (qa[0][1] + bq[0].y)*scale);
        qu.u[1] = pkbf((qa[0][2] + bq[0].z)*scale, (qa[0][3] + bq[0].w)*scale);
        qu.u[2] = pkbf((qa[1][0] + bq[1].x)*scale, (qa[1][1] + bq[1].y)*scale);
        qu.u[3] = pkbf((qa[1][2] + bq[1].z)*scale, (qa[1][3] + bq[1].w)*scale);
        ku.u[0] = pkbf( ka[0][0] + bk[0].x,  ka[0][1] + bk[0].y);
        ku.u[1] = pkbf( ka[0][2] + bk[0].z,  ka[0][3] + bk[0].w);
        ku.u[2] = pkbf( ka[1][0] + bk[1].x,  ka[1][1] + bk[1].y);
        ku.u[3] = pkbf( ka[1][2] + bk[1].z,  ka[1][3] + bk[1].w);
        qf[mt] = qu.s;
        kf[mt] = ku.s;
    }

    // ---- V GEMM per mt-pair msp: only va[2][2] (16 regs) live ----
    // va (normal): va[mtl][dh][r] = V[m=(2*msp+mtl)*16+g*4+r][d=dh*16+ln]
    #pragma unroll
    for (int msp = 0; msp < 2; ++msp) {
        f4 va[2][2];
        #pragma unroll
        for (int mtl = 0; mtl < 2; ++mtl) {
            va[mtl][0] = (f4){0.f,0.f,0.f,0.f};
            va[mtl][1] = (f4){0.f,0.f,0.f,0.f};
        }
        #pragma unroll
        for (int ks = 0; ks < 8; ++ks) {
            s8v xf0 = *(const s8v*)&xs[2*msp  ][ks][lane ^ ks][0];
            s8v xf1 = *(const s8v*)&xs[2*msp+1][ks][lane ^ ks][0];
            s8v wfv[2];
            #pragma unroll
            for (int dh = 0; dh < 2; ++dh)
                wfv[dh] = *(const s8v*)&wq[(size_t)(((32+2*h+dh)*8 + ks)*64 + lane) * 8];
            #pragma unroll
            for (int dh = 0; dh < 2; ++dh) {
                va[0][dh] = MFMA(xf0, wfv[dh], va[0][dh]);   // normal
                va[1][dh] = MFMA(xf1, wfv[dh], va[1][dh]);
            }
        }
        // vf[msp][dh][j] = V[msp*32+kappa(g,j)][dh*16+ln]; va dies here
        #pragma unroll
        for (int dh = 0; dh < 2; ++dh) {
            union { s8v s; unsigned u[4]; } vu;
            vu.u[0] = pkbf(va[0][dh][0] + bv[dh], va[0][dh][1] + bv[dh]);
            vu.u[1] = pkbf(va[0][dh][2] + bv[dh], va[0][dh][3] + bv[dh]);
            vu.u[2] = pkbf(va[1][dh][0] + bv[dh], va[1][dh][1] + bv[dh]);
            vu.u[3] = pkbf(va[1][dh][2] + bv[dh], va[1][dh][3] + bv[dh]);
            vf[msp][dh] = vu.s;
        }
    }

    // ---- attention (per query tile), write O straight to osd ----
    #pragma unroll
    for (int qt = 0; qt < 4; ++qt) {
        // vectorized bias loads, issued before MFMAs (independent -> overlap)
        f4 bias4[4];
        #pragma unroll
        for (int kt = 0; kt < 4; ++kt)
            bias4[kt] = *(const f4*)&biasT2[(size_t)(h*64 + qt*16 + ln)*64 + kt*16 + g*4];

        f4 st[4];
        #pragma unroll
        for (int kt = 0; kt < 4; ++kt) {
            f4 z = (f4){0.f,0.f,0.f,0.f};
            st[kt] = MFMA(kf[kt], qf[qt], z);
        }

        // softmax without max-sub (R15-proven): s = st + bias (VALU add);
        // masked keys -1e30 -> exp 0; padded queries bias 0 -> sum=49.
        float pr[16];
        float sum = 0.f;
        #pragma unroll
        for (int kt = 0; kt < 4; ++kt)
            #pragma unroll
            for (int r = 0; r < 4; ++r) {
                float e = __expf(st[kt][r] + bias4[kt][r]);
                pr[kt*4 + r] = e;
                sum += e;
            }
        sum += __shfl_xor(sum, 16);
        sum += __shfl_xor(sum, 32);
        float rinv = 1.f / sum;

        // pa = normalized P (rinv on the ln=query axis -- matches pr)
        s8v pa[2];
        #pragma unroll
        for (int ksp = 0; ksp < 2; ++ksp) {
            union { s8v s; unsigned u[4]; } pu;
            #pragma unroll
            for (int i2 = 0; i2 < 4; ++i2)
                pu.u[i2] = pkbf(pr[8*ksp + 2*i2] * rinv, pr[8*ksp + 2*i2 + 1] * rinv);
            pa[ksp] = pu.s;
        }

        f4 oacc[2];
        oacc[0] = (f4){0.f,0.f,0.f,0.f};
        oacc[1] = (f4){0.f,0.f,0.f,0.f};
        #pragma unroll
        for (int ksp = 0; ksp < 2; ++ksp)
            #pragma unroll
            for (int dh = 0; dh < 2; ++dh)
                oacc[dh] = MFMA(pa[ksp], vf[ksp][dh], oacc[dh]);

        #pragma unroll
        for (int dh = 0; dh < 2; ++dh)
            #pragma unroll
            for (int r = 0; r < 4; ++r)
                osd[qt*16 + g*4 + r][h*32 + dh*16 + ln] = f2bf(oacc[dh][r]);
    }
    __syncthreads();

    // ---- proj GEMM: out = O @ Wp + b (2 n-tiles per wave) ----
    f4 acc[4][2];
    #pragma unroll
    for (int mt = 0; mt < 4; ++mt)
        #pragma unroll
        for (int t = 0; t < 2; ++t)
            acc[mt][t] = (f4){0.f,0.f,0.f,0.f};

    #pragma unroll
    for (int ks = 0; ks < 8; ++ks) {
        s8v av[4], bw[2];
        #pragma unroll
        for (int mt = 0; mt < 4; ++mt)
            av[mt] = *(const s8v*)&osd[mt*16 + ln][ks*32 + g*8];
        #pragma unroll
        for (int t = 0; t < 2; ++t) {
            int nt = w*2 + t;
            bw[t] = *(const s8v*)&wp[(size_t)((nt*8 + ks)*64 + lane) * 8];
        }
        #pragma unroll
        for (int mt = 0; mt < 4; ++mt)
            #pragma unroll
            for (int t = 0; t < 2; ++t)
                acc[mt][t] = MFMA(av[mt], bw[t], acc[mt][t]);
    }

    float* ob = out + (size_t)b * (49*256);
    #pragma unroll
    for (int t = 0; t < 2; ++t) {
        int n = (w*2 + t)*16 + ln;
        float pb = proj_b[n];
        #pragma unroll
        for (int mt = 0; mt < 4; ++mt)
            #pragma unroll
            for (int r = 0; r < 4; ++r) {
                int q = mt*16 + g*4 + r;
                if (q < 49)
                    ob[q*256 + n] = acc[mt][t][r] + pb;
            }
    }
}

extern "C" void kernel_launch(void* const* d_in, const int* in_sizes, int n_in,
                              void* d_out, int out_size, void* d_ws, size_t ws_size,
                              hipStream_t stream)
{
    (void)n_in; (void)out_size; (void)ws_size;
    const float* x        = (const float*)d_in[0];
    const int*   rel_idx  = (const int*)  d_in[1];
    const float* qkv_w    = (const float*)d_in[2];
    const float* qkv_b    = (const float*)d_in[3];
    const float* rel_bias = (const float*)d_in[4];
    const float* proj_w   = (const float*)d_in[5];
    const float* proj_b   = (const float*)d_in[6];
    float* out = (float*)d_out;

    const int B = in_sizes[0] / (49*256);

    unsigned short* wq = (unsigned short*)d_ws;                     // 393216 B
    unsigned short* wp = wq + 48*8*64*8;                            // 131072 B
    float* biasT2 = (float*)((char*)d_ws + 524288);                 // 131072 B

    prep<<<256, 256, 0, stream>>>(qkv_w, proj_w, rel_bias, rel_idx, wq, wp, biasT2);
    kall<<<B, 512, 0, stream>>>(x, qkv_b, wq, biasT2, wp, proj_b, out);
}

// Round 19
// 273.958 us; speedup vs baseline: 2.0197x; 2.0197x over previous
//
#include <hip/hip_runtime.h>

// Window attention: B=4096, L=49, C=256, H=8, D=32
// prep : weight swizzle (bf16 MFMA frag order) + bias table [h][q][k]
// kall : fully fused qkv GEMM + attention + proj; one block (512 thr, 8 waves)
//        per window, ONE HEAD PER WAVE. (R15 structure, byte-identical except
//        for the s_setprio markers.)
//
// LEDGER (hard-won):
//  - OCCUPANCY FILE CLOSED: live set ~256 unified regs/wave -> 8 waves/CU,
//    (512,2) final. Every cap <=170 spilled 0.3-1.4GB (7 events).
//  - pkbf (v_cvt_pk_bf16_f32 inline asm) is proven ONLY where the 32-bit
//    result is stored/consumed whole (x staging, qf/kf/vf repack, pa pack).
//    Splitting its halves into two separate b16 LDS stores (the osd pack)
//    failed deterministically in R12-R14+R18 (3.509521e-02, identical across
//    otherwise-different builds). osd stays f2bf-per-element. R14's
//    "bias-in-C guilty" verdict was contaminated by this same pack.
//  - no-max-subtraction softmax is PROVEN (R15): padded queries bias 0 ->
//    finite sums; masked keys -1e30 -> exp 0.
//
// R19 = R15 + s_setprio(1) around the two attention MFMA clusters only
// (T5: attn-shaped regime: 8 waves run barrier-free through QKV+attn).
// Tripwire: WRITE_SIZE >> 218MB means spill regression.

typedef short s8v __attribute__((ext_vector_type(8)));   // 8 bf16 (4 VGPRs)
typedef short s4v __attribute__((ext_vector_type(4)));   // 4 bf16 (8B)
typedef float f4  __attribute__((ext_vector_type(4)));   // MFMA C/D frag

#define MFMA(a,b,c) __builtin_amdgcn_mfma_f32_16x16x32_bf16((a),(b),(c),0,0,0)

__device__ __forceinline__ unsigned short f2bf(float f) {
    unsigned u = __float_as_uint(f);
    u = u + 0x7fffu + ((u >> 16) & 1u);   // round-to-nearest-even
    return (unsigned short)(u >> 16);
}

// pack 2 f32 -> u32 of 2 bf16 (lo,hi), RNE, single VALU op (R10-proven
// for whole-word consumers only -- see ledger)
__device__ __forceinline__ unsigned pkbf(float lo, float hi) {
    unsigned r;
    asm("v_cvt_pk_bf16_f32 %0, %1, %2" : "=v"(r) : "v"(lo), "v"(hi));
    return r;
}

// ---------------- prep: weight swizzle + bias table ----------------
// wq layout: [nt=48][ks=8][lane=64][j=8]; element = qkv_w[ks*32+(lane>>4)*8+j][nt*16+(lane&15)]
// wp: same with nt=16 over proj_w
// biasT2: [h=8][query=64][key=64] fp32; key>=49 -> -1e30;
//         padded query (>=49) & key<49 -> 0 (finite softmax sum w/o max-sub)
__global__ void prep(const float* __restrict__ qkv_w, const float* __restrict__ proj_w,
                     const float* __restrict__ rel_bias, const int* __restrict__ rel_idx,
                     unsigned short* __restrict__ wq, unsigned short* __restrict__ wp,
                     float* __restrict__ biasT2)
{
    int idx = blockIdx.x * blockDim.x + threadIdx.x;
    int stride = gridDim.x * blockDim.x;
    for (int i = idx; i < 48*8*64*8; i += stride) {
        int j = i & 7, l = (i >> 3) & 63, ks = (i >> 9) & 7, nt = i >> 12;
        int k = ks*32 + (l >> 4)*8 + j;
        int n = nt*16 + (l & 15);
        wq[i] = f2bf(qkv_w[k*768 + n]);
    }
    for (int i = idx; i < 16*8*64*8; i += stride) {
        int j = i & 7, l = (i >> 3) & 63, ks = (i >> 9) & 7, nt = i >> 12;
        int k = ks*32 + (l >> 4)*8 + j;
        int n = nt*16 + (l & 15);
        wp[i] = f2bf(proj_w[k*256 + n]);
    }
    for (int i = idx; i < 8*64*64; i += stride) {
        int k = i & 63, q = (i >> 6) & 63, h = i >> 12;
        float v;
        if (k < 49) v = (q < 49) ? rel_bias[rel_idx[q*49 + k]*8 + h] : 0.f;
        else        v = -1e30f;
        biasT2[i] = v;
    }
}

// ---------------- kall: fused qkv + attention + proj ----------------
__global__ __launch_bounds__(512, 2) void kall(
    const float* __restrict__ x, const float* __restrict__ qkv_b,
    const unsigned short* __restrict__ wq, const float* __restrict__ biasT2,
    const unsigned short* __restrict__ wp, const float* __restrict__ proj_b,
    float* __restrict__ out)
{
    __shared__ __align__(16) unsigned short xs[4][8][64][8];   // x frags, 32768 B (lane^ks swizzled)
    __shared__ __align__(16) unsigned short osd[64][264];      // O bf16 row-major, 33792 B

    const int b    = blockIdx.x;
    const int tid  = threadIdx.x;
    const int w    = tid >> 6;      // wave = head
    const int lane = tid & 63;
    const int ln   = lane & 15;
    const int g    = lane >> 4;

    // ---- stage x -> frag-layout bf16 LDS (cvt_pk pairs; lane^ks bank swizzle) ----
    const float* xb = x + (size_t)b * (49*256);
    for (int i = tid; i < 4096; i += 512) {
        int r = i >> 6, c4 = i & 63;
        float4 v = make_float4(0.f, 0.f, 0.f, 0.f);
        if (r < 49) v = ((const float4*)xb)[r*64 + c4];
        uint2 o;
        o.x = pkbf(v.x, v.y);
        o.y = pkbf(v.z, v.w);
        int mt = r >> 4, lnr = r & 15;
        int c  = c4 * 4;
        int ks = c >> 5, gg = (c >> 3) & 3, j0 = c & 7;
        *(uint2*)&xs[mt][ks][(gg*16 + lnr) ^ ks][j0] = o;
    }
    __syncthreads();

    const float scale = 0.17677669529663687f;  // 1/sqrt(32)
    const int h = w;                           // this wave's head

    // ---- QKV GEMM ----
    // qa/ka (transposed): qa[dh][mt][r] = Q[m=mt*16+ln][d=dh*16+g*4+r]
    // va (normal):        va[mt][dh][r] = V[m=mt*16+g*4+r][d=dh*16+ln]
    f4 qa[2][4], ka[2][4], va[4][2];
    #pragma unroll
    for (int dh = 0; dh < 2; ++dh)
        #pragma unroll
        for (int mt = 0; mt < 4; ++mt) {
            qa[dh][mt] = (f4){0.f,0.f,0.f,0.f};
            ka[dh][mt] = (f4){0.f,0.f,0.f,0.f};
            va[mt][dh] = (f4){0.f,0.f,0.f,0.f};
        }

    #pragma unroll
    for (int ks = 0; ks < 8; ++ks) {
        s8v xf[4];
        #pragma unroll
        for (int mt = 0; mt < 4; ++mt)
            xf[mt] = *(const s8v*)&xs[mt][ks][lane ^ ks][0];
        s8v wfq[2], wfk[2], wfv[2];
        #pragma unroll
        for (int dh = 0; dh < 2; ++dh) {
            wfq[dh] = *(const s8v*)&wq[(size_t)((( 2*h+dh)*8 + ks)*64 + lane) * 8];
            wfk[dh] = *(const s8v*)&wq[(size_t)(((16+2*h+dh)*8 + ks)*64 + lane) * 8];
            wfv[dh] = *(const s8v*)&wq[(size_t)(((32+2*h+dh)*8 + ks)*64 + lane) * 8];
        }
        #pragma unroll
        for (int dh = 0; dh < 2; ++dh)
            #pragma unroll
            for (int mt = 0; mt < 4; ++mt) {
                qa[dh][mt] = MFMA(wfq[dh], xf[mt], qa[dh][mt]);   // transposed
                ka[dh][mt] = MFMA(wfk[dh], xf[mt], ka[dh][mt]);
                va[mt][dh] = MFMA(xf[mt], wfv[dh], va[mt][dh]);   // normal
            }
    }

    // ---- biases ----
    float4 bq[2], bk[2]; float bv[2];
    #pragma unroll
    for (int dh = 0; dh < 2; ++dh) {
        bq[dh] = *(const float4*)&qkv_b[       h*32 + dh*16 + g*4];
        bk[dh] = *(const float4*)&qkv_b[256 +  h*32 + dh*16 + g*4];
        bv[dh] = qkv_b[512 + h*32 + dh*16 + ln];
    }

    // ---- in-lane repack to bf16 frags (kappa mapping), via cvt_pk pairs ----
    s8v qf[4], kf[4], vf[2][2];
    #pragma unroll
    for (int t = 0; t < 4; ++t) {
        union { s8v s; unsigned u[4]; } qu, ku;
        qu.u[0] = pkbf((qa[0][t][0] + bq[0].x)*scale, (qa[0][t][1] + bq[0].y)*scale);
        qu.u[1] = pkbf((qa[0][t][2] + bq[0].z)*scale, (qa[0][t][3] + bq[0].w)*scale);
        qu.u[2] = pkbf((qa[1][t][0] + bq[1].x)*scale, (qa[1][t][1] + bq[1].y)*scale);
        qu.u[3] = pkbf((qa[1][t][2] + bq[1].z)*scale, (qa[1][t][3] + bq[1].w)*scale);
        ku.u[0] = pkbf( ka[0][t][0] + bk[0].x,  ka[0][t][1] + bk[0].y);
        ku.u[1] = pkbf( ka[0][t][2] + bk[0].z,  ka[0][t][3] + bk[0].w);
        ku.u[2] = pkbf( ka[1][t][0] + bk[1].x,  ka[1][t][1] + bk[1].y);
        ku.u[3] = pkbf( ka[1][t][2] + bk[1].z,  ka[1][t][3] + bk[1].w);
        qf[t] = qu.s;
        kf[t] = ku.s;
    }
    #pragma unroll
    for (int ksp = 0; ksp < 2; ++ksp)
        #pragma unroll
        for (int dh = 0; dh < 2; ++dh) {
            union { s8v s; unsigned u[4]; } vu;
            vu.u[0] = pkbf(va[2*ksp  ][dh][0] + bv[dh], va[2*ksp  ][dh][1] + bv[dh]);
            vu.u[1] = pkbf(va[2*ksp  ][dh][2] + bv[dh], va[2*ksp  ][dh][3] + bv[dh]);
            vu.u[2] = pkbf(va[2*ksp+1][dh][0] + bv[dh], va[2*ksp+1][dh][1] + bv[dh]);
            vu.u[3] = pkbf(va[2*ksp+1][dh][2] + bv[dh], va[2*ksp+1][dh][3] + bv[dh]);
            vf[ksp][dh] = vu.s;
        }

    // ---- attention (per query tile), write O straight to osd ----
    #pragma unroll
    for (int qt = 0; qt < 4; ++qt) {
        // vectorized bias loads, issued before MFMAs (independent -> overlap)
        f4 bias4[4];
        #pragma unroll
        for (int kt = 0; kt < 4; ++kt)
            bias4[kt] = *(const f4*)&biasT2[(size_t)(h*64 + qt*16 + ln)*64 + kt*16 + g*4];

        __builtin_amdgcn_s_setprio(1);
        f4 st[4];
        #pragma unroll
        for (int kt = 0; kt < 4; ++kt) {
            f4 z = (f4){0.f,0.f,0.f,0.f};
            st[kt] = MFMA(kf[kt], qf[qt], z);
        }
        __builtin_amdgcn_s_setprio(0);

        // softmax WITHOUT max-subtraction (R15-proven):
        // s = st + bias (VALU add); masked keys -1e30 -> exp 0;
        // padded queries bias 0 -> sum=49 finite.
        float pr[16];
        float sum = 0.f;
        #pragma unroll
        for (int kt = 0; kt < 4; ++kt)
            #pragma unroll
            for (int r = 0; r < 4; ++r) {
                float e = __expf(st[kt][r] + bias4[kt][r]);
                pr[kt*4 + r] = e;
                sum += e;
            }
        sum += __shfl_xor(sum, 16);
        sum += __shfl_xor(sum, 32);
        float rinv = 1.f / sum;

        // pa = normalized P (rinv on the ln=query axis -- matches pr)
        s8v pa[2];
        #pragma unroll
        for (int ksp = 0; ksp < 2; ++ksp) {
            union { s8v s; unsigned u[4]; } pu;
            #pragma unroll
            for (int i2 = 0; i2 < 4; ++i2)
                pu.u[i2] = pkbf(pr[8*ksp + 2*i2] * rinv, pr[8*ksp + 2*i2 + 1] * rinv);
            pa[ksp] = pu.s;
        }

        __builtin_amdgcn_s_setprio(1);
        f4 oacc[2];
        oacc[0] = (f4){0.f,0.f,0.f,0.f};
        oacc[1] = (f4){0.f,0.f,0.f,0.f};
        #pragma unroll
        for (int ksp = 0; ksp < 2; ++ksp)
            #pragma unroll
            for (int dh = 0; dh < 2; ++dh)
                oacc[dh] = MFMA(pa[ksp], vf[ksp][dh], oacc[dh]);
        __builtin_amdgcn_s_setprio(0);

        // osd store: f2bf PER ELEMENT (pkbf-split-halves is radioactive here)
        #pragma unroll
        for (int dh = 0; dh < 2; ++dh)
            #pragma unroll
            for (int r = 0; r < 4; ++r)
                osd[qt*16 + g*4 + r][h*32 + dh*16 + ln] = f2bf(oacc[dh][r]);
    }
    __syncthreads();

    // ---- proj GEMM: out = O @ Wp + b (2 n-tiles per wave) ----
    f4 acc[4][2];
    #pragma unroll
    for (int mt = 0; mt < 4; ++mt)
        #pragma unroll
        for (int t = 0; t < 2; ++t)
            acc[mt][t] = (f4){0.f,0.f,0.f,0.f};

    #pragma unroll
    for (int ks = 0; ks < 8; ++ks) {
        s8v av[4], bw[2];
        #pragma unroll
        for (int mt = 0; mt < 4; ++mt)
            av[mt] = *(const s8v*)&osd[mt*16 + ln][ks*32 + g*8];
        #pragma unroll
        for (int t = 0; t < 2; ++t) {
            int nt = w*2 + t;
            bw[t] = *(const s8v*)&wp[(size_t)((nt*8 + ks)*64 + lane) * 8];
        }
        #pragma unroll
        for (int mt = 0; mt < 4; ++mt)
            #pragma unroll
            for (int t = 0; t < 2; ++t)
                acc[mt][t] = MFMA(av[mt], bw[t], acc[mt][t]);
    }

    float* ob = out + (size_t)b * (49*256);
    #pragma unroll
    for (int t = 0; t < 2; ++t) {
        int n = (w*2 + t)*16 + ln;
        float pb = proj_b[n];
        #pragma unroll
        for (int mt = 0; mt < 4; ++mt)
            #pragma unroll
            for (int r = 0; r < 4; ++r) {
                int q = mt*16 + g*4 + r;
                if (q < 49)
                    ob[q*256 + n] = acc[mt][t][r] + pb;
            }
    }
}

extern "C" void kernel_launch(void* const* d_in, const int* in_sizes, int n_in,
                              void* d_out, int out_size, void* d_ws, size_t ws_size,
                              hipStream_t stream)
{
    (void)n_in; (void)out_size; (void)ws_size;
    const float* x        = (const float*)d_in[0];
    const int*   rel_idx  = (const int*)  d_in[1];
    const float* qkv_w    = (const float*)d_in[2];
    const float* qkv_b    = (const float*)d_in[3];
    const float* rel_bias = (const float*)d_in[4];
    const float* proj_w   = (const float*)d_in[5];
    const float* proj_b   = (const float*)d_in[6];
    float* out = (float*)d_out;

    const int B = in_sizes[0] / (49*256);

    unsigned short* wq = (unsigned short*)d_ws;                     // 393216 B
    unsigned short* wp = wq + 48*8*64*8;                            // 131072 B
    float* biasT2 = (float*)((char*)d_ws + 524288);                 // 131072 B

    prep<<<256, 256, 0, stream>>>(qkv_w, proj_w, rel_bias, rel_idx, wq, wp, biasT2);
    kall<<<B, 512, 0, stream>>>(x, qkv_b, wq, biasT2, wp, proj_b, out);
}